// Round 1
// baseline (1656.350 us; speedup 1.0000x reference)
//
#include <hip/hip_runtime.h>
#include <hip/hip_bf16.h>

// Problem: Bahdanau attention. B=128, T=576, D=1024, H=1024, U=512. All fp32.
// out = concat(context[B,D], attention_weights[B,T])
#define B_ 128
#define T_ 576
#define D_ 1024
#define H_ 1024
#define U_ 512

// ---------------------------------------------------------------------------
// K1: projh[b,u] = hidden[b,:] @ W2[:,u] + W2_b[u] + W1_b[u]
// (W1_b folded in since both biases are added before tanh)
// grid: B_ blocks, 512 threads
__global__ __launch_bounds__(512) void projh_kernel(
    const float* __restrict__ hidden, const float* __restrict__ W2,
    const float* __restrict__ W2b, const float* __restrict__ W1b,
    float* __restrict__ projh) {
  const int b = blockIdx.x;
  const int u = threadIdx.x;
  __shared__ float sh[256];
  float acc = 0.f;
  for (int h0 = 0; h0 < H_; h0 += 256) {
    if (threadIdx.x < 256) sh[threadIdx.x] = hidden[b * H_ + h0 + threadIdx.x];
    __syncthreads();
#pragma unroll 8
    for (int hh = 0; hh < 256; ++hh)
      acc += sh[hh] * W2[(h0 + hh) * U_ + u];
    __syncthreads();
  }
  projh[b * U_ + u] = acc + W2b[u] + W1b[u];
}

// ---------------------------------------------------------------------------
// K2: score[b,t] = sum_u tanh(features[b,t,:]@W1[:,u] + projh[b,u]) * Vw[u] + Vb
// Tiled fp32 GEMM fused with tanh/V epilogue; proj_f never materialized.
// BM=32 (t rows), BN=128 (u chunk, 4 chunks), BK=32. 256 threads, 4x4 microtile.
// grid: (T_/32, B_)
__global__ __launch_bounds__(256) void score_kernel(
    const float* __restrict__ features, const float* __restrict__ W1,
    const float* __restrict__ projh, const float* __restrict__ Vw,
    const float* __restrict__ Vb, float* __restrict__ score) {
  const int b = blockIdx.y;
  const int t0 = blockIdx.x * 32;
  const int tid = threadIdx.x;
  const int tx = tid & 31;  // col group: cols u = tx + 32*j
  const int ty = tid >> 5;  // row group: rows t = ty + 8*i
  __shared__ float As[32][36];   // +4 pad keeps 16B row alignment, kills stride conflicts
  __shared__ float Bs[32][128];
  float stot[4] = {0.f, 0.f, 0.f, 0.f};
  const float* fbase = features + ((long)b * T_ + t0) * D_;

  for (int u0 = 0; u0 < U_; u0 += 128) {
    float acc[4][4] = {};
    for (int k0 = 0; k0 < D_; k0 += 32) {
      // stage A: 32x32 tile of features, one float4 per thread
      {
        const int row = tid >> 3, c4 = (tid & 7) * 4;
        const float4 f = *(const float4*)(fbase + (long)row * D_ + k0 + c4);
        As[row][c4 + 0] = f.x; As[row][c4 + 1] = f.y;
        As[row][c4 + 2] = f.z; As[row][c4 + 3] = f.w;
      }
      // stage B: 32x128 tile of W1, four float4 per thread
#pragma unroll
      for (int i = 0; i < 4; ++i) {
        const int row = (tid >> 5) + i * 8;
        const int c4 = (tid & 31) * 4;
        *(float4*)&Bs[row][c4] =
            *(const float4*)(W1 + (long)(k0 + row) * U_ + u0 + c4);
      }
      __syncthreads();
#pragma unroll
      for (int kk = 0; kk < 32; ++kk) {
        float a[4], bv[4];
#pragma unroll
        for (int i = 0; i < 4; ++i) a[i] = As[ty + 8 * i][kk];
#pragma unroll
        for (int j = 0; j < 4; ++j) bv[j] = Bs[kk][tx + 32 * j];
#pragma unroll
        for (int i = 0; i < 4; ++i)
#pragma unroll
          for (int j = 0; j < 4; ++j) acc[i][j] += a[i] * bv[j];
      }
      __syncthreads();
    }
    // epilogue for this u-chunk: bias-add, tanh, V-weighted reduce
#pragma unroll
    for (int j = 0; j < 4; ++j) {
      const int u = u0 + tx + 32 * j;
      const float ph = projh[b * U_ + u];
      const float vw = Vw[u];
#pragma unroll
      for (int i = 0; i < 4; ++i)
        stot[i] += tanhf(acc[i][j] + ph) * vw;
    }
  }
  // reduce across the 32 tx lanes (each 32-subgroup owns fixed rows)
#pragma unroll
  for (int i = 0; i < 4; ++i) {
    float v = stot[i];
    for (int off = 16; off > 0; off >>= 1) v += __shfl_xor(v, off, 32);
    if (tx == 0) score[b * T_ + t0 + ty + 8 * i] = v + Vb[0];
  }
}

// ---------------------------------------------------------------------------
// K3: softmax over T per batch. grid: B_, 256 threads (576 = 256+256+64)
__global__ __launch_bounds__(256) void softmax_kernel(
    const float* __restrict__ score, float* __restrict__ wout) {
  const int b = blockIdx.x;
  const int tid = threadIdx.x;
  __shared__ float red[256];
  const float v0 = score[b * T_ + tid];
  const float v1 = score[b * T_ + 256 + tid];
  const float v2 = (tid < 64) ? score[b * T_ + 512 + tid] : -1e30f;
  red[tid] = fmaxf(fmaxf(v0, v1), v2);
  __syncthreads();
  for (int s = 128; s > 0; s >>= 1) {
    if (tid < s) red[tid] = fmaxf(red[tid], red[tid + s]);
    __syncthreads();
  }
  const float mx = red[0];
  __syncthreads();
  const float e0 = expf(v0 - mx), e1 = expf(v1 - mx);
  const float e2 = (tid < 64) ? expf(v2 - mx) : 0.f;
  red[tid] = e0 + e1 + e2;
  __syncthreads();
  for (int s = 128; s > 0; s >>= 1) {
    if (tid < s) red[tid] += red[tid + s];
    __syncthreads();
  }
  const float inv = 1.f / red[0];
  wout[b * T_ + tid] = e0 * inv;
  wout[b * T_ + 256 + tid] = e1 * inv;
  if (tid < 64) wout[b * T_ + 512 + tid] = e2 * inv;
}

// ---------------------------------------------------------------------------
// K4: context[b,d] = sum_t w[b,t] * features[b,t,d]. grid: B_, 256 threads,
// each thread owns 4 consecutive d (float4).
__global__ __launch_bounds__(256) void context_kernel(
    const float* __restrict__ features, const float* __restrict__ w,
    float* __restrict__ ctx) {
  const int b = blockIdx.x;
  const int tid = threadIdx.x;
  __shared__ float sw[T_];
  for (int t = tid; t < T_; t += 256) sw[t] = w[b * T_ + t];
  __syncthreads();
  const float* fb = features + (long)b * T_ * D_ + tid * 4;
  float4 acc = {0.f, 0.f, 0.f, 0.f};
#pragma unroll 4
  for (int t = 0; t < T_; ++t) {
    const float4 f = *(const float4*)(fb + (long)t * D_);
    const float wt = sw[t];
    acc.x += wt * f.x; acc.y += wt * f.y;
    acc.z += wt * f.z; acc.w += wt * f.w;
  }
  *(float4*)(ctx + b * D_ + tid * 4) = acc;
}

// ---------------------------------------------------------------------------
extern "C" void kernel_launch(void* const* d_in, const int* in_sizes, int n_in,
                              void* d_out, int out_size, void* d_ws,
                              size_t ws_size, hipStream_t stream) {
  const float* features = (const float*)d_in[0];  // [B,T,D]
  const float* hidden   = (const float*)d_in[1];  // [B,H]
  const float* W1_w     = (const float*)d_in[2];  // [D,U]
  const float* W1_b     = (const float*)d_in[3];  // [U]
  const float* W2_w     = (const float*)d_in[4];  // [H,U]
  const float* W2_b     = (const float*)d_in[5];  // [U]
  const float* V_w      = (const float*)d_in[6];  // [U,1]
  const float* V_b      = (const float*)d_in[7];  // [1]

  float* out_ctx  = (float*)d_out;            // [B,D]
  float* out_attn = out_ctx + B_ * D_;        // [B,T]
  float* projh    = (float*)d_ws;             // [B,U]
  float* score    = projh + B_ * U_;          // [B,T]

  projh_kernel<<<B_, 512, 0, stream>>>(hidden, W2_w, W2_b, W1_b, projh);
  score_kernel<<<dim3(T_ / 32, B_), 256, 0, stream>>>(features, W1_w, projh,
                                                      V_w, V_b, score);
  softmax_kernel<<<B_, 256, 0, stream>>>(score, out_attn);
  context_kernel<<<B_, 256, 0, stream>>>(features, out_attn, out_ctx);
}

// Round 2
// 735.603 us; speedup vs baseline: 2.2517x; 2.2517x over previous
//
#include <hip/hip_runtime.h>

// Bahdanau attention. B=128, T=576, D=1024, H=1024, U=512. fp32 in/out.
// out = concat(context[B,D], attention_weights[B,T])
#define B_ 128
#define T_ 576
#define D_ 1024
#define H_ 1024
#define U_ 512

typedef short bf16x8 __attribute__((ext_vector_type(8)));
typedef float f32x4 __attribute__((ext_vector_type(4)));

__device__ inline unsigned short f2bf(float f) {
  union { float f; unsigned u; } v; v.f = f;
  unsigned r = v.u + 0x7FFF + ((v.u >> 16) & 1);  // RNE
  return (unsigned short)(r >> 16);
}

__device__ inline float fast_tanh(float x) {
  float e = __expf(2.f * x);           // v_exp_f32 path
  return 1.f - 2.f / (e + 1.f);        // saturates correctly at +/-1
}

// ---------------------------------------------------------------------------
// P0: W1 [D,U] fp32 -> W1T [U,D] bf16 (one-shot, ~2 MB). Makes B-fragments
// k-contiguous in the MFMA kernel. grid (D/32, U/32), 256 threads.
__global__ __launch_bounds__(256) void w1t_kernel(
    const float* __restrict__ W1, unsigned short* __restrict__ W1T) {
  __shared__ float tile[32][33];
  const int k0 = blockIdx.x * 32, u0 = blockIdx.y * 32;
  const int tx = threadIdx.x & 31, ty = threadIdx.x >> 5;  // 32 x 8
#pragma unroll
  for (int i = 0; i < 32; i += 8)
    tile[ty + i][tx] = W1[(k0 + ty + i) * U_ + u0 + tx];
  __syncthreads();
#pragma unroll
  for (int i = 0; i < 32; i += 8)
    W1T[(u0 + ty + i) * D_ + k0 + tx] = f2bf(tile[tx][ty + i]);
}

// ---------------------------------------------------------------------------
// K1: projh[b,u] = hidden[b,:] @ W2[:,u] + W2_b[u] + W1_b[u]
__global__ __launch_bounds__(512) void projh_kernel(
    const float* __restrict__ hidden, const float* __restrict__ W2,
    const float* __restrict__ W2b, const float* __restrict__ W1b,
    float* __restrict__ projh) {
  const int b = blockIdx.x;
  const int u = threadIdx.x;
  __shared__ float sh[256];
  float acc = 0.f;
  for (int h0 = 0; h0 < H_; h0 += 256) {
    if (threadIdx.x < 256) sh[threadIdx.x] = hidden[b * H_ + h0 + threadIdx.x];
    __syncthreads();
#pragma unroll 8
    for (int hh = 0; hh < 256; ++hh)
      acc += sh[hh] * W2[(h0 + hh) * U_ + u];
    __syncthreads();
  }
  projh[b * U_ + u] = acc + W2b[u] + W1b[u];
}

// ---------------------------------------------------------------------------
// K2: score[b,t] = sum_u tanh( (features[b,t,:]@W1[:,u])_bf16mfma + projh[b,u] ) * Vw[u] + Vb
// MFMA 16x16x32 bf16. Block tile BM=64 (t) x BN=128 (u-chunk, 4 chunks looped
// in-block so features are staged/read once per K-tile per chunk but never
// re-read across an N-grid split). 256 threads = 4 waves, wave tile 32x64.
#define BM 64
#define BN 128
#define BK 64
#define LDST 72  // BK + 8 ushort pad: fragment rows 2-way bank alias only (free)
__global__ __launch_bounds__(256) void score_mfma_kernel(
    const float* __restrict__ features, const unsigned short* __restrict__ W1T,
    const float* __restrict__ projh, const float* __restrict__ Vw,
    const float* __restrict__ Vb, float* __restrict__ score) {
  __shared__ unsigned short As[BM][LDST];
  __shared__ unsigned short Bs[BN][LDST];
  __shared__ float sred[2][BM];
  const int b = blockIdx.y;
  const int t0 = blockIdx.x * BM;
  const int tid = threadIdx.x;
  const int lane = tid & 63;
  const int w = tid >> 6;
  const int wm = w & 1, wn = w >> 1;     // wave tile: rows wm*32+, cols wn*64+
  const int m16 = lane & 15, quad = lane >> 4;
  const float* fbase = features + ((long)b * T_ + t0) * D_;

  float stot[2][4] = {{0.f, 0.f, 0.f, 0.f}, {0.f, 0.f, 0.f, 0.f}};

  for (int u0 = 0; u0 < U_; u0 += BN) {
    f32x4 acc[2][4];
#pragma unroll
    for (int i = 0; i < 2; ++i)
#pragma unroll
      for (int j = 0; j < 4; ++j) acc[i][j] = (f32x4){0.f, 0.f, 0.f, 0.f};

    for (int kt = 0; kt < D_; kt += BK) {
      // stage A: 64x64 fp32 -> bf16 (float4 per thread x4, coalesced)
#pragma unroll
      for (int i = 0; i < 4; ++i) {
        const int q = tid + 256 * i;
        const int row = q >> 4, c4 = (q & 15) * 4;
        const float4 f = *(const float4*)(fbase + (long)row * D_ + kt + c4);
        ushort4 h;
        h.x = f2bf(f.x); h.y = f2bf(f.y); h.z = f2bf(f.z); h.w = f2bf(f.w);
        *(ushort4*)&As[row][c4] = h;
      }
      // stage B: already bf16 [n][k] in W1T, 16B copies
#pragma unroll
      for (int i = 0; i < 4; ++i) {
        const int q = tid + 256 * i;
        const int n = q >> 3, k8 = (q & 7) * 8;
        *(uint4*)&Bs[n][k8] =
            *(const uint4*)(W1T + ((u0 + n) << 10) + kt + k8);
      }
      __syncthreads();
#pragma unroll
      for (int ks = 0; ks < BK; ks += 32) {
        bf16x8 a[2], bb[4];
#pragma unroll
        for (int i = 0; i < 2; ++i)
          a[i] = *(const bf16x8*)&As[wm * 32 + i * 16 + m16][ks + quad * 8];
#pragma unroll
        for (int j = 0; j < 4; ++j)
          bb[j] = *(const bf16x8*)&Bs[wn * 64 + j * 16 + m16][ks + quad * 8];
#pragma unroll
        for (int i = 0; i < 2; ++i)
#pragma unroll
          for (int j = 0; j < 4; ++j)
            acc[i][j] = __builtin_amdgcn_mfma_f32_16x16x32_bf16(
                a[i], bb[j], acc[i][j], 0, 0, 0);
      }
      __syncthreads();
    }
    // epilogue: bias + tanh + V-weighted partial sum.
    // C/D layout: col(u) = lane&15, row(t) = quad*4 + reg.
#pragma unroll
    for (int j = 0; j < 4; ++j) {
      const int u = u0 + wn * 64 + j * 16 + m16;
      const float ph = projh[b * U_ + u];
      const float vw = Vw[u];
#pragma unroll
      for (int i = 0; i < 2; ++i)
#pragma unroll
        for (int r = 0; r < 4; ++r)
          stot[i][r] += vw * fast_tanh(acc[i][j][r] + ph);
    }
  }
  // reduce the 16 u-columns held across lanes (lane&15) within each quad
#pragma unroll
  for (int i = 0; i < 2; ++i)
#pragma unroll
    for (int r = 0; r < 4; ++r) {
      float v = stot[i][r];
      v += __shfl_xor(v, 1, 16);
      v += __shfl_xor(v, 2, 16);
      v += __shfl_xor(v, 4, 16);
      v += __shfl_xor(v, 8, 16);
      if (m16 == 0) sred[wn][wm * 32 + i * 16 + quad * 4 + r] = v;
    }
  __syncthreads();
  if (tid < BM)
    score[b * T_ + t0 + tid] = sred[0][tid] + sred[1][tid] + Vb[0];
}

// ---------------------------------------------------------------------------
// K3: softmax over T per batch. grid B_, 256 threads (576 = 256+256+64)
__global__ __launch_bounds__(256) void softmax_kernel(
    const float* __restrict__ score, float* __restrict__ wout) {
  const int b = blockIdx.x;
  const int tid = threadIdx.x;
  __shared__ float red[256];
  const float v0 = score[b * T_ + tid];
  const float v1 = score[b * T_ + 256 + tid];
  const float v2 = (tid < 64) ? score[b * T_ + 512 + tid] : -1e30f;
  red[tid] = fmaxf(fmaxf(v0, v1), v2);
  __syncthreads();
  for (int s = 128; s > 0; s >>= 1) {
    if (tid < s) red[tid] = fmaxf(red[tid], red[tid + s]);
    __syncthreads();
  }
  const float mx = red[0];
  __syncthreads();
  const float e0 = expf(v0 - mx), e1 = expf(v1 - mx);
  const float e2 = (tid < 64) ? expf(v2 - mx) : 0.f;
  red[tid] = e0 + e1 + e2;
  __syncthreads();
  for (int s = 128; s > 0; s >>= 1) {
    if (tid < s) red[tid] += red[tid + s];
    __syncthreads();
  }
  const float inv = 1.f / red[0];
  wout[b * T_ + tid] = e0 * inv;
  wout[b * T_ + 256 + tid] = e1 * inv;
  if (tid < 64) wout[b * T_ + 512 + tid] = e2 * inv;
}

// ---------------------------------------------------------------------------
// K4: context[b,d] = sum_t w[b,t] * features[b,t,d]. grid (B_, 8) x 128 thr
// (1024 blocks -> 4 blocks/CU; per-wave row reads are 256B contiguous).
__global__ __launch_bounds__(128) void context_kernel(
    const float* __restrict__ features, const float* __restrict__ w,
    float* __restrict__ ctx) {
  const int b = blockIdx.x;
  const int d = blockIdx.y * 128 + threadIdx.x;
  __shared__ float sw[T_];
  for (int t = threadIdx.x; t < T_; t += 128) sw[t] = w[b * T_ + t];
  __syncthreads();
  const float* fb = features + (long)b * T_ * D_ + d;
  float acc = 0.f;
#pragma unroll 8
  for (int t = 0; t < T_; ++t) acc += sw[t] * fb[(long)t * D_];
  ctx[b * D_ + d] = acc;
}

// ---------------------------------------------------------------------------
extern "C" void kernel_launch(void* const* d_in, const int* in_sizes, int n_in,
                              void* d_out, int out_size, void* d_ws,
                              size_t ws_size, hipStream_t stream) {
  const float* features = (const float*)d_in[0];  // [B,T,D]
  const float* hidden   = (const float*)d_in[1];  // [B,H]
  const float* W1_w     = (const float*)d_in[2];  // [D,U]
  const float* W1_b     = (const float*)d_in[3];  // [U]
  const float* W2_w     = (const float*)d_in[4];  // [H,U]
  const float* W2_b     = (const float*)d_in[5];  // [U]
  const float* V_w      = (const float*)d_in[6];  // [U,1]
  const float* V_b      = (const float*)d_in[7];  // [1]

  float* out_ctx  = (float*)d_out;      // [B,D]
  float* out_attn = out_ctx + B_ * D_;  // [B,T]

  char* ws = (char*)d_ws;
  float* projh = (float*)ws;                               // 256 KB
  float* score = (float*)(ws + 256 * 1024);                // 288 KB
  unsigned short* W1T = (unsigned short*)(ws + 1024 * 1024);  // 1 MB

  w1t_kernel<<<dim3(D_ / 32, U_ / 32), 256, 0, stream>>>(W1_w, W1T);
  projh_kernel<<<B_, 512, 0, stream>>>(hidden, W2_w, W2_b, W1_b, projh);
  score_mfma_kernel<<<dim3(T_ / BM, B_), 256, 0, stream>>>(
      features, W1T, projh, V_w, V_b, score);
  softmax_kernel<<<B_, 256, 0, stream>>>(score, out_attn);
  context_kernel<<<dim3(B_, 8), 128, 0, stream>>>(features, out_attn, out_ctx);
}

// Round 4
// 701.552 us; speedup vs baseline: 2.3610x; 1.0485x over previous
//
#include <hip/hip_runtime.h>
#include <hip/hip_bf16.h>

// Bahdanau attention. B=128, T=576, D=1024, H=1024, U=512. fp32 in/out.
// out = concat(context[B,D], attention_weights[B,T])
//
// R4 note: R3's 144MB bf16-feature precompute in d_ws caused deterministic
// post-timing divergence (suspected poison/ws interaction at high ws offsets;
// R2's 2MB-window ws usage was stable). This version uses ONE unconditional
// path and keeps all ws usage in the first ~2.6 MB.
#define B_ 128
#define T_ 576
#define D_ 1024
#define H_ 1024
#define U_ 512
#define M_ (B_ * T_)  // 73728 flattened (b,t) rows

typedef short bf16x8 __attribute__((ext_vector_type(8)));
typedef float f32x4 __attribute__((ext_vector_type(4)));

__device__ inline unsigned short f2bf(float f) {
  union { float f; unsigned u; } v; v.f = f;
  unsigned r = v.u + 0x7FFF + ((v.u >> 16) & 1);  // RNE
  return (unsigned short)(r >> 16);
}

// packed fp32x2 -> bf16x2 (v_cvt_pk_bf16_f32 on gfx950), RNE
__device__ inline unsigned int pkcvt(float x, float y) {
  union { __hip_bfloat162 b2; unsigned int u; } v;
  v.b2 = __float22bfloat162_rn(make_float2(x, y));
  return v.u;  // low short = x, high short = y
}

__device__ inline float fast_tanh(float x) {
  float e = __expf(2.f * x);
  return 1.f - 2.f / (e + 1.f);
}

// ---------------------------------------------------------------------------
// P0: W1 [D,U] fp32 -> W1T [U,D] bf16 (k-contiguous B fragments).
__global__ __launch_bounds__(256) void w1t_kernel(
    const float* __restrict__ W1, unsigned short* __restrict__ W1T) {
  __shared__ float tile[32][33];
  const int k0 = blockIdx.x * 32, u0 = blockIdx.y * 32;
  const int tx = threadIdx.x & 31, ty = threadIdx.x >> 5;
#pragma unroll
  for (int i = 0; i < 32; i += 8)
    tile[ty + i][tx] = W1[(k0 + ty + i) * U_ + u0 + tx];
  __syncthreads();
#pragma unroll
  for (int i = 0; i < 32; i += 8)
    W1T[(u0 + ty + i) * D_ + k0 + tx] = f2bf(tile[tx][ty + i]);
}

// ---------------------------------------------------------------------------
// K1: projh[b,u] = hidden[b,:] @ W2[:,u] + W2_b[u] + W1_b[u]
__global__ __launch_bounds__(512) void projh_kernel(
    const float* __restrict__ hidden, const float* __restrict__ W2,
    const float* __restrict__ W2b, const float* __restrict__ W1b,
    float* __restrict__ projh) {
  const int b = blockIdx.x;
  const int u = threadIdx.x;
  __shared__ float sh[256];
  float acc = 0.f;
  for (int h0 = 0; h0 < H_; h0 += 256) {
    if (threadIdx.x < 256) sh[threadIdx.x] = hidden[b * H_ + h0 + threadIdx.x];
    __syncthreads();
#pragma unroll 8
    for (int hh = 0; hh < 256; ++hh)
      acc += sh[hh] * W2[(h0 + hh) * U_ + u];
    __syncthreads();
  }
  projh[b * U_ + u] = acc + W2b[u] + W1b[u];
}

// ---------------------------------------------------------------------------
// K2: spart[chunk, r] = sum_{u in chunk} tanh(feat[r,:]@W1[:,u] + projh[b(r),u]) * Vw[u]
// Flattened M = B*T. Block 128(M) x 128(u-chunk), BK=64, 4 waves, 64x64 wave
// tile (4x4 of 16x16x32 bf16 MFMA). u-chunks on gridDim.y (partials additive).
// A is fp32, converted in staging via packed cvt.
#define LDST 72  // 64 + 8 ushort pad
__global__ __launch_bounds__(256) void score_mfma3(
    const float* __restrict__ feat, const unsigned short* __restrict__ W1T,
    const float* __restrict__ projh, const float* __restrict__ Vw,
    float* __restrict__ spart) {
  __shared__ unsigned short As[128][LDST];
  __shared__ unsigned short Bs[128][LDST];
  __shared__ float phs[2][128];
  __shared__ float vws[128];
  __shared__ float sred[2][128];
  const int tid = threadIdx.x;
  const int chunk = blockIdx.y, u0 = chunk * 128;
  const int t0 = blockIdx.x * 128;
  const int b0 = t0 / T_, b1 = (t0 + 127) / T_;
  const int bsplit = (b0 + 1) * T_;  // rows >= bsplit belong to b1
  const int lane = tid & 63, w = tid >> 6;
  const int wm = w & 1, wn = w >> 1;  // wave tile origin (wm*64, wn*64)
  const int m16 = lane & 15, quad = lane >> 4;

  if (tid < 128) vws[tid] = Vw[u0 + tid];
  phs[tid >> 7][tid & 127] =
      projh[((tid >> 7) ? b1 : b0) * U_ + u0 + (tid & 127)];

  f32x4 acc[4][4];
#pragma unroll
  for (int i = 0; i < 4; ++i)
#pragma unroll
    for (int j = 0; j < 4; ++j) acc[i][j] = (f32x4){0.f, 0.f, 0.f, 0.f};

  for (int kt = 0; kt < D_; kt += 64) {
    // stage A: 128x64 fp32 -> bf16 via packed cvt. 8 float4/thread, coalesced
    // (16 lanes cover one row's 256B k-segment).
#pragma unroll
    for (int i = 0; i < 8; ++i) {
      const int q = tid + 256 * i;
      const int row = q >> 4, c4 = (q & 15) * 4;
      const float4 f =
          *(const float4*)(feat + ((long)(t0 + row) << 10) + kt + c4);
      uint2 p;
      p.x = pkcvt(f.x, f.y);
      p.y = pkcvt(f.z, f.w);
      *(uint2*)&As[row][c4] = p;
    }
    // stage B: already bf16 [n][k] in W1T, 16B copies
#pragma unroll
    for (int i = 0; i < 4; ++i) {
      const int q = tid + 256 * i;
      const int row = q >> 3, k8 = (q & 7) * 8;
      *(uint4*)&Bs[row][k8] =
          *(const uint4*)(W1T + ((long)(u0 + row) << 10) + kt + k8);
    }
    __syncthreads();
#pragma unroll
    for (int ks = 0; ks < 64; ks += 32) {
      bf16x8 a[4], bb[4];
#pragma unroll
      for (int i = 0; i < 4; ++i)
        a[i] = *(const bf16x8*)&As[wm * 64 + i * 16 + m16][ks + quad * 8];
#pragma unroll
      for (int j = 0; j < 4; ++j)
        bb[j] = *(const bf16x8*)&Bs[wn * 64 + j * 16 + m16][ks + quad * 8];
#pragma unroll
      for (int i = 0; i < 4; ++i)
#pragma unroll
        for (int j = 0; j < 4; ++j)
          acc[i][j] = __builtin_amdgcn_mfma_f32_16x16x32_bf16(
              a[i], bb[j], acc[i][j], 0, 0, 0);
    }
    __syncthreads();
  }

  // epilogue: tanh + V-weighted partial sum over this chunk's 128 u columns.
  // C/D layout: col(u) = lane&15, row(t) = quad*4 + reg.
  float stot[4][4] = {};
#pragma unroll
  for (int j = 0; j < 4; ++j) {
    const int ul = wn * 64 + j * 16 + m16;
    const float vw = vws[ul];
    const float ph0 = phs[0][ul], ph1 = phs[1][ul];
#pragma unroll
    for (int i = 0; i < 4; ++i) {
      const int rbase = t0 + wm * 64 + i * 16 + quad * 4;
#pragma unroll
      for (int r = 0; r < 4; ++r) {
        const float ph = (rbase + r >= bsplit) ? ph1 : ph0;
        stot[i][r] += vw * fast_tanh(acc[i][j][r] + ph);
      }
    }
  }
  // reduce 16 u-columns across lanes (m16) within each quad
#pragma unroll
  for (int i = 0; i < 4; ++i)
#pragma unroll
    for (int r = 0; r < 4; ++r) {
      float v = stot[i][r];
      v += __shfl_xor(v, 1, 16);
      v += __shfl_xor(v, 2, 16);
      v += __shfl_xor(v, 4, 16);
      v += __shfl_xor(v, 8, 16);
      if (m16 == 0) sred[wn][wm * 64 + i * 16 + quad * 4 + r] = v;
    }
  __syncthreads();
  if (tid < 128)
    spart[(long)chunk * M_ + t0 + tid] = sred[0][tid] + sred[1][tid];
}

// ---------------------------------------------------------------------------
// K3: softmax over T per batch; sums the 4 u-chunk partials. (V_b dropped:
// softmax is shift-invariant.) grid B_, 256 threads (576 = 256+256+64).
__global__ __launch_bounds__(256) void softmax_kernel(
    const float* __restrict__ sp, float* __restrict__ wout) {
  const int b = blockIdx.x;
  const int tid = threadIdx.x;
  __shared__ float red[256];
  auto ld = [&](int t) -> float {
    const long r = (long)b * T_ + t;
    return sp[r] + sp[M_ + r] + sp[2L * M_ + r] + sp[3L * M_ + r];
  };
  const float v0 = ld(tid);
  const float v1 = ld(tid + 256);
  const float v2 = (tid < 64) ? ld(tid + 512) : -1e30f;
  red[tid] = fmaxf(fmaxf(v0, v1), v2);
  __syncthreads();
  for (int s = 128; s > 0; s >>= 1) {
    if (tid < s) red[tid] = fmaxf(red[tid], red[tid + s]);
    __syncthreads();
  }
  const float mx = red[0];
  __syncthreads();
  const float e0 = expf(v0 - mx), e1 = expf(v1 - mx);
  const float e2 = (tid < 64) ? expf(v2 - mx) : 0.f;
  red[tid] = e0 + e1 + e2;
  __syncthreads();
  for (int s = 128; s > 0; s >>= 1) {
    if (tid < s) red[tid] += red[tid + s];
    __syncthreads();
  }
  const float inv = 1.f / red[0];
  wout[b * T_ + tid] = e0 * inv;
  wout[b * T_ + 256 + tid] = e1 * inv;
  if (tid < 64) wout[b * T_ + 512 + tid] = e2 * inv;
}

// ---------------------------------------------------------------------------
// K4: context[b,d] = sum_t w[b,t] * features[b,t,d]. grid (B_, 8) x 128 thr
// (R2-proven; 1024 blocks -> 4 blocks/CU; wave row reads 256B contiguous).
__global__ __launch_bounds__(128) void context_kernel(
    const float* __restrict__ features, const float* __restrict__ w,
    float* __restrict__ ctx) {
  const int b = blockIdx.x;
  const int d = blockIdx.y * 128 + threadIdx.x;
  __shared__ float sw[T_];
  for (int t = threadIdx.x; t < T_; t += 128) sw[t] = w[b * T_ + t];
  __syncthreads();
  const float* fb = features + (long)b * T_ * D_ + d;
  float acc = 0.f;
#pragma unroll 8
  for (int t = 0; t < T_; ++t) acc += sw[t] * fb[(long)t * D_];
  ctx[b * D_ + d] = acc;
}

// ---------------------------------------------------------------------------
extern "C" void kernel_launch(void* const* d_in, const int* in_sizes, int n_in,
                              void* d_out, int out_size, void* d_ws,
                              size_t ws_size, hipStream_t stream) {
  const float* features = (const float*)d_in[0];  // [B,T,D]
  const float* hidden   = (const float*)d_in[1];  // [B,H]
  const float* W1_w     = (const float*)d_in[2];  // [D,U]
  const float* W1_b     = (const float*)d_in[3];  // [U]
  const float* W2_w     = (const float*)d_in[4];  // [H,U]
  const float* W2_b     = (const float*)d_in[5];  // [U]
  const float* V_w      = (const float*)d_in[6];  // [U,1]
  const float* V_b      = (const float*)d_in[7];  // [1] (unused: softmax shift-invariant)
  (void)V_b;

  float* out_ctx  = (float*)d_out;      // [B,D]
  float* out_attn = out_ctx + B_ * D_;  // [B,T]

  char* ws = (char*)d_ws;
  float* projh        = (float*)ws;                      // 256 KB @ 0
  float* spart        = (float*)(ws + 0x40000);          // 1.18 MB @ 256K
  unsigned short* W1T = (unsigned short*)(ws + 0x180000);  // 1 MB @ 1.5M
  // total ws window: 2.62 MB (single unconditional path)

  w1t_kernel<<<dim3(D_ / 32, U_ / 32), 256, 0, stream>>>(W1_w, W1T);
  projh_kernel<<<B_, 512, 0, stream>>>(hidden, W2_w, W2_b, W1_b, projh);
  score_mfma3<<<dim3(M_ / 128, 4), 256, 0, stream>>>(features, W1T, projh,
                                                     V_w, spart);
  softmax_kernel<<<B_, 256, 0, stream>>>(spart, out_attn);
  context_kernel<<<dim3(B_, 8), 128, 0, stream>>>(features, out_attn, out_ctx);
}

// Round 5
// 651.453 us; speedup vs baseline: 2.5425x; 1.0769x over previous
//
#include <hip/hip_runtime.h>
#include <hip/hip_bf16.h>

// Bahdanau attention. B=128, T=576, D=1024, H=1024, U=512. fp32 in/out.
// out = concat(context[B,D], attention_weights[B,T])
//
// R5: identical math to R4 (proven correct, absmax 9.8e-4). One change:
// u-chunk index moved to blockIdx.x (fastest-varying) so the 4 blocks
// sharing a feature tile dispatch adjacently -> L3 absorbs the 4x re-read.
// R4 evidence: FETCH 599 MB ~= 2x features = HBM-bound at 2.2 TB/s.
#define B_ 128
#define T_ 576
#define D_ 1024
#define H_ 1024
#define U_ 512
#define M_ (B_ * T_)  // 73728 flattened (b,t) rows

typedef short bf16x8 __attribute__((ext_vector_type(8)));
typedef float f32x4 __attribute__((ext_vector_type(4)));

__device__ inline unsigned short f2bf(float f) {
  union { float f; unsigned u; } v; v.f = f;
  unsigned r = v.u + 0x7FFF + ((v.u >> 16) & 1);  // RNE
  return (unsigned short)(r >> 16);
}

// packed fp32x2 -> bf16x2 (v_cvt_pk_bf16_f32 on gfx950), RNE
__device__ inline unsigned int pkcvt(float x, float y) {
  union { __hip_bfloat162 b2; unsigned int u; } v;
  v.b2 = __float22bfloat162_rn(make_float2(x, y));
  return v.u;
}

__device__ inline float fast_tanh(float x) {
  float e = __expf(2.f * x);
  return 1.f - 2.f / (e + 1.f);
}

// ---------------------------------------------------------------------------
// P0: W1 [D,U] fp32 -> W1T [U,D] bf16 (k-contiguous B fragments).
__global__ __launch_bounds__(256) void w1t_kernel(
    const float* __restrict__ W1, unsigned short* __restrict__ W1T) {
  __shared__ float tile[32][33];
  const int k0 = blockIdx.x * 32, u0 = blockIdx.y * 32;
  const int tx = threadIdx.x & 31, ty = threadIdx.x >> 5;
#pragma unroll
  for (int i = 0; i < 32; i += 8)
    tile[ty + i][tx] = W1[(k0 + ty + i) * U_ + u0 + tx];
  __syncthreads();
#pragma unroll
  for (int i = 0; i < 32; i += 8)
    W1T[(u0 + ty + i) * D_ + k0 + tx] = f2bf(tile[tx][ty + i]);
}

// ---------------------------------------------------------------------------
// K1: projh[b,u] = hidden[b,:] @ W2[:,u] + W2_b[u] + W1_b[u]
__global__ __launch_bounds__(512) void projh_kernel(
    const float* __restrict__ hidden, const float* __restrict__ W2,
    const float* __restrict__ W2b, const float* __restrict__ W1b,
    float* __restrict__ projh) {
  const int b = blockIdx.x;
  const int u = threadIdx.x;
  __shared__ float sh[256];
  float acc = 0.f;
  for (int h0 = 0; h0 < H_; h0 += 256) {
    if (threadIdx.x < 256) sh[threadIdx.x] = hidden[b * H_ + h0 + threadIdx.x];
    __syncthreads();
#pragma unroll 8
    for (int hh = 0; hh < 256; ++hh)
      acc += sh[hh] * W2[(h0 + hh) * U_ + u];
    __syncthreads();
  }
  projh[b * U_ + u] = acc + W2b[u] + W1b[u];
}

// ---------------------------------------------------------------------------
// K2: spart[chunk, r] = sum_{u in chunk} tanh(feat[r,:]@W1[:,u] + projh[b(r),u]) * Vw[u]
// Flattened M = B*T. Block 128(M) x 128(u-chunk), BK=64, 4 waves, 64x64 wave
// tile (4x4 of 16x16x32 bf16 MFMA). chunk = blockIdx.x (fastest) for L3 reuse.
#define LDST 72  // 64 + 8 ushort pad
__global__ __launch_bounds__(256) void score_mfma3(
    const float* __restrict__ feat, const unsigned short* __restrict__ W1T,
    const float* __restrict__ projh, const float* __restrict__ Vw,
    float* __restrict__ spart) {
  __shared__ unsigned short As[128][LDST];
  __shared__ unsigned short Bs[128][LDST];
  __shared__ float phs[2][128];
  __shared__ float vws[128];
  __shared__ float sred[2][128];
  const int tid = threadIdx.x;
  const int chunk = blockIdx.x, u0 = chunk * 128;   // fastest-varying
  const int t0 = blockIdx.y * 128;
  const int b0 = t0 / T_, b1 = (t0 + 127) / T_;
  const int bsplit = (b0 + 1) * T_;  // rows >= bsplit belong to b1
  const int lane = tid & 63, w = tid >> 6;
  const int wm = w & 1, wn = w >> 1;  // wave tile origin (wm*64, wn*64)
  const int m16 = lane & 15, quad = lane >> 4;

  if (tid < 128) vws[tid] = Vw[u0 + tid];
  phs[tid >> 7][tid & 127] =
      projh[((tid >> 7) ? b1 : b0) * U_ + u0 + (tid & 127)];

  f32x4 acc[4][4];
#pragma unroll
  for (int i = 0; i < 4; ++i)
#pragma unroll
    for (int j = 0; j < 4; ++j) acc[i][j] = (f32x4){0.f, 0.f, 0.f, 0.f};

  for (int kt = 0; kt < D_; kt += 64) {
    // stage A: 128x64 fp32 -> bf16 via packed cvt. 8 float4/thread, coalesced
    // (16 lanes cover one row's 256B k-segment).
#pragma unroll
    for (int i = 0; i < 8; ++i) {
      const int q = tid + 256 * i;
      const int row = q >> 4, c4 = (q & 15) * 4;
      const float4 f =
          *(const float4*)(feat + ((long)(t0 + row) << 10) + kt + c4);
      uint2 p;
      p.x = pkcvt(f.x, f.y);
      p.y = pkcvt(f.z, f.w);
      *(uint2*)&As[row][c4] = p;
    }
    // stage B: already bf16 [n][k] in W1T, 16B copies
#pragma unroll
    for (int i = 0; i < 4; ++i) {
      const int q = tid + 256 * i;
      const int row = q >> 3, k8 = (q & 7) * 8;
      *(uint4*)&Bs[row][k8] =
          *(const uint4*)(W1T + ((long)(u0 + row) << 10) + kt + k8);
    }
    __syncthreads();
#pragma unroll
    for (int ks = 0; ks < 64; ks += 32) {
      bf16x8 a[4], bb[4];
#pragma unroll
      for (int i = 0; i < 4; ++i)
        a[i] = *(const bf16x8*)&As[wm * 64 + i * 16 + m16][ks + quad * 8];
#pragma unroll
      for (int j = 0; j < 4; ++j)
        bb[j] = *(const bf16x8*)&Bs[wn * 64 + j * 16 + m16][ks + quad * 8];
#pragma unroll
      for (int i = 0; i < 4; ++i)
#pragma unroll
        for (int j = 0; j < 4; ++j)
          acc[i][j] = __builtin_amdgcn_mfma_f32_16x16x32_bf16(
              a[i], bb[j], acc[i][j], 0, 0, 0);
    }
    __syncthreads();
  }

  // epilogue: tanh + V-weighted partial sum over this chunk's 128 u columns.
  // C/D layout: col(u) = lane&15, row(t) = quad*4 + reg.
  float stot[4][4] = {};
#pragma unroll
  for (int j = 0; j < 4; ++j) {
    const int ul = wn * 64 + j * 16 + m16;
    const float vw = vws[ul];
    const float ph0 = phs[0][ul], ph1 = phs[1][ul];
#pragma unroll
    for (int i = 0; i < 4; ++i) {
      const int rbase = t0 + wm * 64 + i * 16 + quad * 4;
#pragma unroll
      for (int r = 0; r < 4; ++r) {
        const float ph = (rbase + r >= bsplit) ? ph1 : ph0;
        stot[i][r] += vw * fast_tanh(acc[i][j][r] + ph);
      }
    }
  }
  // reduce 16 u-columns across lanes (m16) within each quad
#pragma unroll
  for (int i = 0; i < 4; ++i)
#pragma unroll
    for (int r = 0; r < 4; ++r) {
      float v = stot[i][r];
      v += __shfl_xor(v, 1, 16);
      v += __shfl_xor(v, 2, 16);
      v += __shfl_xor(v, 4, 16);
      v += __shfl_xor(v, 8, 16);
      if (m16 == 0) sred[wn][wm * 64 + i * 16 + quad * 4 + r] = v;
    }
  __syncthreads();
  if (tid < 128)
    spart[(long)chunk * M_ + t0 + tid] = sred[0][tid] + sred[1][tid];
}

// ---------------------------------------------------------------------------
// K3: softmax over T per batch; sums the 4 u-chunk partials. (V_b dropped:
// softmax is shift-invariant.) grid B_, 256 threads (576 = 256+256+64).
__global__ __launch_bounds__(256) void softmax_kernel(
    const float* __restrict__ sp, float* __restrict__ wout) {
  const int b = blockIdx.x;
  const int tid = threadIdx.x;
  __shared__ float red[256];
  auto ld = [&](int t) -> float {
    const long r = (long)b * T_ + t;
    return sp[r] + sp[M_ + r] + sp[2L * M_ + r] + sp[3L * M_ + r];
  };
  const float v0 = ld(tid);
  const float v1 = ld(tid + 256);
  const float v2 = (tid < 64) ? ld(tid + 512) : -1e30f;
  red[tid] = fmaxf(fmaxf(v0, v1), v2);
  __syncthreads();
  for (int s = 128; s > 0; s >>= 1) {
    if (tid < s) red[tid] = fmaxf(red[tid], red[tid + s]);
    __syncthreads();
  }
  const float mx = red[0];
  __syncthreads();
  const float e0 = expf(v0 - mx), e1 = expf(v1 - mx);
  const float e2 = (tid < 64) ? expf(v2 - mx) : 0.f;
  red[tid] = e0 + e1 + e2;
  __syncthreads();
  for (int s = 128; s > 0; s >>= 1) {
    if (tid < s) red[tid] += red[tid + s];
    __syncthreads();
  }
  const float inv = 1.f / red[0];
  wout[b * T_ + tid] = e0 * inv;
  wout[b * T_ + 256 + tid] = e1 * inv;
  if (tid < 64) wout[b * T_ + 512 + tid] = e2 * inv;
}

// ---------------------------------------------------------------------------
// K4: context[b,d] = sum_t w[b,t] * features[b,t,d]. grid (B_, 8) x 128 thr.
__global__ __launch_bounds__(128) void context_kernel(
    const float* __restrict__ features, const float* __restrict__ w,
    float* __restrict__ ctx) {
  const int b = blockIdx.x;
  const int d = blockIdx.y * 128 + threadIdx.x;
  __shared__ float sw[T_];
  for (int t = threadIdx.x; t < T_; t += 128) sw[t] = w[b * T_ + t];
  __syncthreads();
  const float* fb = features + (long)b * T_ * D_ + d;
  float acc = 0.f;
#pragma unroll 8
  for (int t = 0; t < T_; ++t) acc += sw[t] * fb[(long)t * D_];
  ctx[b * D_ + d] = acc;
}

// ---------------------------------------------------------------------------
extern "C" void kernel_launch(void* const* d_in, const int* in_sizes, int n_in,
                              void* d_out, int out_size, void* d_ws,
                              size_t ws_size, hipStream_t stream) {
  const float* features = (const float*)d_in[0];  // [B,T,D]
  const float* hidden   = (const float*)d_in[1];  // [B,H]
  const float* W1_w     = (const float*)d_in[2];  // [D,U]
  const float* W1_b     = (const float*)d_in[3];  // [U]
  const float* W2_w     = (const float*)d_in[4];  // [H,U]
  const float* W2_b     = (const float*)d_in[5];  // [U]
  const float* V_w      = (const float*)d_in[6];  // [U,1]
  const float* V_b      = (const float*)d_in[7];  // [1] (unused: softmax shift-invariant)
  (void)V_b;

  float* out_ctx  = (float*)d_out;      // [B,D]
  float* out_attn = out_ctx + B_ * D_;  // [B,T]

  char* ws = (char*)d_ws;
  float* projh        = (float*)ws;                      // 256 KB @ 0
  float* spart        = (float*)(ws + 0x40000);          // 1.18 MB @ 256K
  unsigned short* W1T = (unsigned short*)(ws + 0x180000);  // 1 MB @ 1.5M
  // total ws window: 2.62 MB (single unconditional path)

  w1t_kernel<<<dim3(D_ / 32, U_ / 32), 256, 0, stream>>>(W1_w, W1T);
  projh_kernel<<<B_, 512, 0, stream>>>(hidden, W2_w, W2_b, W1_b, projh);
  score_mfma3<<<dim3(4, M_ / 128), 256, 0, stream>>>(features, W1T, projh,
                                                     V_w, spart);
  softmax_kernel<<<B_, 256, 0, stream>>>(spart, out_attn);
  context_kernel<<<dim3(B_, 8), 128, 0, stream>>>(features, out_attn, out_ctx);
}

// Round 6
// 636.347 us; speedup vs baseline: 2.6029x; 1.0237x over previous
//
#include <hip/hip_runtime.h>
#include <hip/hip_bf16.h>

// Bahdanau attention. B=128, T=576, D=1024, H=1024, U=512. fp32 in/out.
// out = concat(context[B,D], attention_weights[B,T])
//
// R6: identical math to R5 (proven, absmax 9.8e-4). One change: XCD-aware
// grid swizzle. The 4 u-chunk blocks sharing one feature tile get linear IDs
// 8/16/24 apart -> same XCD under id%8 round-robin AND co-resident ->
// the 128x1024 fp32 tile is fetched into that XCD's L2 once, not 4x.
// R5 evidence: FETCH 595 MB ~= 2x features; L3 absorbed some (bw 2.46 TB/s)
// but L2-miss traffic is the limiter.
#define B_ 128
#define T_ 576
#define D_ 1024
#define H_ 1024
#define U_ 512
#define M_ (B_ * T_)  // 73728 flattened (b,t) rows

typedef short bf16x8 __attribute__((ext_vector_type(8)));
typedef float f32x4 __attribute__((ext_vector_type(4)));

__device__ inline unsigned short f2bf(float f) {
  union { float f; unsigned u; } v; v.f = f;
  unsigned r = v.u + 0x7FFF + ((v.u >> 16) & 1);  // RNE
  return (unsigned short)(r >> 16);
}

// packed fp32x2 -> bf16x2 (v_cvt_pk_bf16_f32 on gfx950), RNE
__device__ inline unsigned int pkcvt(float x, float y) {
  union { __hip_bfloat162 b2; unsigned int u; } v;
  v.b2 = __float22bfloat162_rn(make_float2(x, y));
  return v.u;
}

__device__ inline float fast_tanh(float x) {
  float e = __expf(2.f * x);
  return 1.f - 2.f / (e + 1.f);
}

// ---------------------------------------------------------------------------
// P0: W1 [D,U] fp32 -> W1T [U,D] bf16 (k-contiguous B fragments).
__global__ __launch_bounds__(256) void w1t_kernel(
    const float* __restrict__ W1, unsigned short* __restrict__ W1T) {
  __shared__ float tile[32][33];
  const int k0 = blockIdx.x * 32, u0 = blockIdx.y * 32;
  const int tx = threadIdx.x & 31, ty = threadIdx.x >> 5;
#pragma unroll
  for (int i = 0; i < 32; i += 8)
    tile[ty + i][tx] = W1[(k0 + ty + i) * U_ + u0 + tx];
  __syncthreads();
#pragma unroll
  for (int i = 0; i < 32; i += 8)
    W1T[(u0 + ty + i) * D_ + k0 + tx] = f2bf(tile[tx][ty + i]);
}

// ---------------------------------------------------------------------------
// K1: projh[b,u] = hidden[b,:] @ W2[:,u] + W2_b[u] + W1_b[u]
__global__ __launch_bounds__(512) void projh_kernel(
    const float* __restrict__ hidden, const float* __restrict__ W2,
    const float* __restrict__ W2b, const float* __restrict__ W1b,
    float* __restrict__ projh) {
  const int b = blockIdx.x;
  const int u = threadIdx.x;
  __shared__ float sh[256];
  float acc = 0.f;
  for (int h0 = 0; h0 < H_; h0 += 256) {
    if (threadIdx.x < 256) sh[threadIdx.x] = hidden[b * H_ + h0 + threadIdx.x];
    __syncthreads();
#pragma unroll 8
    for (int hh = 0; hh < 256; ++hh)
      acc += sh[hh] * W2[(h0 + hh) * U_ + u];
    __syncthreads();
  }
  projh[b * U_ + u] = acc + W2b[u] + W1b[u];
}

// ---------------------------------------------------------------------------
// K2: spart[chunk, r] = sum_{u in chunk} tanh(feat[r,:]@W1[:,u] + projh[b(r),u]) * Vw[u]
// Flattened M = B*T. Block 128(M) x 128(u-chunk), BK=64, 4 waves, 64x64 wave
// tile (4x4 of 16x16x32 bf16 MFMA). 1-D grid, XCD-aware swizzle (see header).
#define LDST 72  // 64 + 8 ushort pad
__global__ __launch_bounds__(256) void score_mfma3(
    const float* __restrict__ feat, const unsigned short* __restrict__ W1T,
    const float* __restrict__ projh, const float* __restrict__ Vw,
    float* __restrict__ spart) {
  __shared__ unsigned short As[128][LDST];
  __shared__ unsigned short Bs[128][LDST];
  __shared__ float phs[2][128];
  __shared__ float vws[128];
  __shared__ float sred[2][128];
  const int tid = threadIdx.x;
  // XCD swizzle: siblings (same t_block, chunk 0..3) differ by 8 in linear id
  // -> same XCD under id%8 round-robin, co-resident -> L2 tile reuse.
  const int lin = blockIdx.x;             // 0..2303
  const int tg = lin >> 5;                // t-group of 8 tiles
  const int rem = lin & 31;
  const int chunk = rem >> 3;             // 0..3
  const int tb = (tg << 3) + (rem & 7);   // 0..575
  const int u0 = chunk * 128;
  const int t0 = tb * 128;
  const int b0 = t0 / T_, b1 = (t0 + 127) / T_;
  const int bsplit = (b0 + 1) * T_;  // rows >= bsplit belong to b1
  const int lane = tid & 63, w = tid >> 6;
  const int wm = w & 1, wn = w >> 1;  // wave tile origin (wm*64, wn*64)
  const int m16 = lane & 15, quad = lane >> 4;

  if (tid < 128) vws[tid] = Vw[u0 + tid];
  phs[tid >> 7][tid & 127] =
      projh[((tid >> 7) ? b1 : b0) * U_ + u0 + (tid & 127)];

  f32x4 acc[4][4];
#pragma unroll
  for (int i = 0; i < 4; ++i)
#pragma unroll
    for (int j = 0; j < 4; ++j) acc[i][j] = (f32x4){0.f, 0.f, 0.f, 0.f};

  for (int kt = 0; kt < D_; kt += 64) {
    // stage A: 128x64 fp32 -> bf16 via packed cvt. 8 float4/thread, coalesced
    // (16 lanes cover one row's 256B k-segment).
#pragma unroll
    for (int i = 0; i < 8; ++i) {
      const int q = tid + 256 * i;
      const int row = q >> 4, c4 = (q & 15) * 4;
      const float4 f =
          *(const float4*)(feat + ((long)(t0 + row) << 10) + kt + c4);
      uint2 p;
      p.x = pkcvt(f.x, f.y);
      p.y = pkcvt(f.z, f.w);
      *(uint2*)&As[row][c4] = p;
    }
    // stage B: already bf16 [n][k] in W1T, 16B copies
#pragma unroll
    for (int i = 0; i < 4; ++i) {
      const int q = tid + 256 * i;
      const int row = q >> 3, k8 = (q & 7) * 8;
      *(uint4*)&Bs[row][k8] =
          *(const uint4*)(W1T + ((long)(u0 + row) << 10) + kt + k8);
    }
    __syncthreads();
#pragma unroll
    for (int ks = 0; ks < 64; ks += 32) {
      bf16x8 a[4], bb[4];
#pragma unroll
      for (int i = 0; i < 4; ++i)
        a[i] = *(const bf16x8*)&As[wm * 64 + i * 16 + m16][ks + quad * 8];
#pragma unroll
      for (int j = 0; j < 4; ++j)
        bb[j] = *(const bf16x8*)&Bs[wn * 64 + j * 16 + m16][ks + quad * 8];
#pragma unroll
      for (int i = 0; i < 4; ++i)
#pragma unroll
        for (int j = 0; j < 4; ++j)
          acc[i][j] = __builtin_amdgcn_mfma_f32_16x16x32_bf16(
              a[i], bb[j], acc[i][j], 0, 0, 0);
    }
    __syncthreads();
  }

  // epilogue: tanh + V-weighted partial sum over this chunk's 128 u columns.
  // C/D layout: col(u) = lane&15, row(t) = quad*4 + reg.
  float stot[4][4] = {};
#pragma unroll
  for (int j = 0; j < 4; ++j) {
    const int ul = wn * 64 + j * 16 + m16;
    const float vw = vws[ul];
    const float ph0 = phs[0][ul], ph1 = phs[1][ul];
#pragma unroll
    for (int i = 0; i < 4; ++i) {
      const int rbase = t0 + wm * 64 + i * 16 + quad * 4;
#pragma unroll
      for (int r = 0; r < 4; ++r) {
        const float ph = (rbase + r >= bsplit) ? ph1 : ph0;
        stot[i][r] += vw * fast_tanh(acc[i][j][r] + ph);
      }
    }
  }
  // reduce 16 u-columns across lanes (m16) within each quad
#pragma unroll
  for (int i = 0; i < 4; ++i)
#pragma unroll
    for (int r = 0; r < 4; ++r) {
      float v = stot[i][r];
      v += __shfl_xor(v, 1, 16);
      v += __shfl_xor(v, 2, 16);
      v += __shfl_xor(v, 4, 16);
      v += __shfl_xor(v, 8, 16);
      if (m16 == 0) sred[wn][wm * 64 + i * 16 + quad * 4 + r] = v;
    }
  __syncthreads();
  if (tid < 128)
    spart[(long)chunk * M_ + t0 + tid] = sred[0][tid] + sred[1][tid];
}

// ---------------------------------------------------------------------------
// K3: softmax over T per batch; sums the 4 u-chunk partials. (V_b dropped:
// softmax is shift-invariant.) grid B_, 256 threads (576 = 256+256+64).
__global__ __launch_bounds__(256) void softmax_kernel(
    const float* __restrict__ sp, float* __restrict__ wout) {
  const int b = blockIdx.x;
  const int tid = threadIdx.x;
  __shared__ float red[256];
  auto ld = [&](int t) -> float {
    const long r = (long)b * T_ + t;
    return sp[r] + sp[M_ + r] + sp[2L * M_ + r] + sp[3L * M_ + r];
  };
  const float v0 = ld(tid);
  const float v1 = ld(tid + 256);
  const float v2 = (tid < 64) ? ld(tid + 512) : -1e30f;
  red[tid] = fmaxf(fmaxf(v0, v1), v2);
  __syncthreads();
  for (int s = 128; s > 0; s >>= 1) {
    if (tid < s) red[tid] = fmaxf(red[tid], red[tid + s]);
    __syncthreads();
  }
  const float mx = red[0];
  __syncthreads();
  const float e0 = expf(v0 - mx), e1 = expf(v1 - mx);
  const float e2 = (tid < 64) ? expf(v2 - mx) : 0.f;
  red[tid] = e0 + e1 + e2;
  __syncthreads();
  for (int s = 128; s > 0; s >>= 1) {
    if (tid < s) red[tid] += red[tid + s];
    __syncthreads();
  }
  const float inv = 1.f / red[0];
  wout[b * T_ + tid] = e0 * inv;
  wout[b * T_ + 256 + tid] = e1 * inv;
  if (tid < 64) wout[b * T_ + 512 + tid] = e2 * inv;
}

// ---------------------------------------------------------------------------
// K4: context[b,d] = sum_t w[b,t] * features[b,t,d]. grid (B_, 8) x 128 thr.
__global__ __launch_bounds__(128) void context_kernel(
    const float* __restrict__ features, const float* __restrict__ w,
    float* __restrict__ ctx) {
  const int b = blockIdx.x;
  const int d = blockIdx.y * 128 + threadIdx.x;
  __shared__ float sw[T_];
  for (int t = threadIdx.x; t < T_; t += 128) sw[t] = w[b * T_ + t];
  __syncthreads();
  const float* fb = features + (long)b * T_ * D_ + d;
  float acc = 0.f;
#pragma unroll 8
  for (int t = 0; t < T_; ++t) acc += sw[t] * fb[(long)t * D_];
  ctx[b * D_ + d] = acc;
}

// ---------------------------------------------------------------------------
extern "C" void kernel_launch(void* const* d_in, const int* in_sizes, int n_in,
                              void* d_out, int out_size, void* d_ws,
                              size_t ws_size, hipStream_t stream) {
  const float* features = (const float*)d_in[0];  // [B,T,D]
  const float* hidden   = (const float*)d_in[1];  // [B,H]
  const float* W1_w     = (const float*)d_in[2];  // [D,U]
  const float* W1_b     = (const float*)d_in[3];  // [U]
  const float* W2_w     = (const float*)d_in[4];  // [H,U]
  const float* W2_b     = (const float*)d_in[5];  // [U]
  const float* V_w      = (const float*)d_in[6];  // [U,1]
  const float* V_b      = (const float*)d_in[7];  // [1] (unused: softmax shift-invariant)
  (void)V_b;

  float* out_ctx  = (float*)d_out;      // [B,D]
  float* out_attn = out_ctx + B_ * D_;  // [B,T]

  char* ws = (char*)d_ws;
  float* projh        = (float*)ws;                      // 256 KB @ 0
  float* spart        = (float*)(ws + 0x40000);          // 1.18 MB @ 256K
  unsigned short* W1T = (unsigned short*)(ws + 0x180000);  // 1 MB @ 1.5M
  // total ws window: 2.62 MB (single unconditional path)

  w1t_kernel<<<dim3(D_ / 32, U_ / 32), 256, 0, stream>>>(W1_w, W1T);
  projh_kernel<<<B_, 512, 0, stream>>>(hidden, W2_w, W2_b, W1_b, projh);
  score_mfma3<<<2304, 256, 0, stream>>>(features, W1T, projh, V_w, spart);
  softmax_kernel<<<B_, 256, 0, stream>>>(spart, out_attn);
  context_kernel<<<dim3(B_, 8), 128, 0, stream>>>(features, out_attn, out_ctx);
}